// Round 14
// baseline (170.753 us; speedup 1.0000x reference)
//
#include <hip/hip_runtime.h>
#include <cstdint>
#include <cstddef>

// Block-diagonal GRU on MI355X (gfx950), fully fused bf16 MFMA path.
// B=8192, IN=1024, H=2048, NB=8, BS=256, 3H=6144.
// Round 14: R13 structure + CONVOY-BREAK STAGGER. Measured: LDS-read demand
// (~1920 cyc) == MFMA demand (~1862) per K-tile-pair per CU, wall ~ their SUM
// -> the 2 co-resident blocks run phase-locked (identical code, simultaneous
// start, LDS contention synchronizes burst phases). Fix: odd-parity blocks
// s_sleep ~960 cyc after prologue staging, pushing block pairs into
// anti-phase (A reads while B MFMAs). Parity (bid>>3)^(bid>>8) covers
// co-residency patterns differing by 8 or 256.

typedef __attribute__((ext_vector_type(8))) short bf16x8;
typedef __attribute__((ext_vector_type(4))) float f32x4;

__device__ __forceinline__ unsigned short f2bf(float f) {
    uint32_t u = __float_as_uint(f);
    u += 0x7FFFu + ((u >> 16) & 1u);   // round-to-nearest-even
    return (unsigned short)(u >> 16);
}
__device__ __forceinline__ float bf2f(unsigned short b) {
    return __uint_as_float(((uint32_t)b) << 16);
}

__device__ __forceinline__ void gload16(const void* g, void* l) {
    __builtin_amdgcn_global_load_lds(
        (const __attribute__((address_space(1))) void*)g,
        (__attribute__((address_space(3))) void*)l,
        16, 0, 0);
}

__device__ __forceinline__ float sigmoidf_(float x) {
    return 1.0f / (1.0f + __expf(-x));
}
__device__ __forceinline__ float tanhf_(float x) {
    float e = __expf(-2.0f * fabsf(x));
    float t = (1.0f - e) / (1.0f + e);
    return copysignf(t, x);
}

// ---------------------------------------------------------------- one cast
// regions (in float4 units): x 2097152 | W_ir 1572864 | h 4194304 | W_h 393216
__global__ __launch_bounds__(256)
void cast_all(const float* __restrict__ x, const float* __restrict__ wir,
              const float* __restrict__ h, const float* __restrict__ wh,
              unsigned short* __restrict__ xb, unsigned short* __restrict__ wirb,
              unsigned short* __restrict__ hb, unsigned short* __restrict__ whb) {
    const int i = blockIdx.x * 256 + threadIdx.x;
    const float* s; unsigned short* d; int j;
    if (i < 2097152)      { s = x;   d = xb;   j = i; }
    else if (i < 3670016) { s = wir; d = wirb; j = i - 2097152; }
    else if (i < 7864320) { s = h;   d = hb;   j = i - 3670016; }
    else                  { s = wh;  d = whb;  j = i - 7864320; }
    const float4 v = *reinterpret_cast<const float4*>(s + (size_t)j * 4);
    ushort4 o;
    o.x = f2bf(v.x); o.y = f2bf(v.y); o.z = f2bf(v.z); o.w = f2bf(v.w);
    *reinterpret_cast<ushort4*>(d + (size_t)j * 4) = o;
}

// ---------------------------------------------------------------- fused GRU
// acc groups: 0=r(sum of both GEMMs), 1=z(sum), 2=wxn, 3=whn.
// NT = 2 during phase1 (x @ W_ir^T), 3 during phase2 (hb @ W_h[kb]^T).
// A tile 128x64 (4 chunks of 32 rows), B tile 192x64 (6 chunks).
// Staging issues/thread/K-tile: 10 = [B0..B3] + [B4,B5,A0,A1] + [A2,A3].
// LDS rows 128 B, T2 XOR-swizzle byte^=(row&7)<<4 via inverse-swizzled
// global source (linear gload_lds dest) + swizzled ds_read (G21).

#define MM12(mb, NT) do {                                                      \
    asm volatile("s_waitcnt lgkmcnt(0)" ::: "memory");                         \
    __builtin_amdgcn_sched_barrier(0);                                         \
    __builtin_amdgcn_s_setprio(1);                                             \
    _Pragma("unroll")                                                          \
    for (int m_ = 0; m_ < 2; ++m_) {                                           \
        acc[0][(mb) + m_][0] = __builtin_amdgcn_mfma_f32_16x16x32_bf16(        \
            av[m_], bv[0][0], acc[0][(mb) + m_][0], 0, 0, 0);                  \
        acc[0][(mb) + m_][1] = __builtin_amdgcn_mfma_f32_16x16x32_bf16(        \
            av[m_], bv[0][1], acc[0][(mb) + m_][1], 0, 0, 0);                  \
        acc[1][(mb) + m_][0] = __builtin_amdgcn_mfma_f32_16x16x32_bf16(        \
            av[m_], bv[1][0], acc[1][(mb) + m_][0], 0, 0, 0);                  \
        acc[1][(mb) + m_][1] = __builtin_amdgcn_mfma_f32_16x16x32_bf16(        \
            av[m_], bv[1][1], acc[1][(mb) + m_][1], 0, 0, 0);                  \
        acc[NT][(mb) + m_][0] = __builtin_amdgcn_mfma_f32_16x16x32_bf16(       \
            av[m_], bv[2][0], acc[NT][(mb) + m_][0], 0, 0, 0);                 \
        acc[NT][(mb) + m_][1] = __builtin_amdgcn_mfma_f32_16x16x32_bf16(       \
            av[m_], bv[2][1], acc[NT][(mb) + m_][1], 0, 0, 0);                 \
    }                                                                          \
    __builtin_amdgcn_s_setprio(0);                                             \
} while (0)

#define RDAV(mb, kb_) do {                                                     \
    av[0] = *(const bf16x8*)(aS + (wm * 64 + ((mb) + 0) * 16 + fr) * 64 + (kb_)); \
    av[1] = *(const bf16x8*)(aS + (wm * 64 + ((mb) + 1) * 16 + fr) * 64 + (kb_)); \
} while (0)
#define RDBV(kb_) do {                                                         \
    _Pragma("unroll")                                                          \
    for (int s_ = 0; s_ < 3; ++s_) {                                           \
        bv[s_][0] = *(const bf16x8*)(bS + ((s_) * 64 + wn * 32 + 0 * 16 + fr) * 64 + (kb_)); \
        bv[s_][1] = *(const bf16x8*)(bS + ((s_) * 64 + wn * 32 + 1 * 16 + fr) * 64 + (kb_)); \
    }                                                                          \
} while (0)

// phase1 staging groups (kt in units of 64 elements along K=1024)
#define I0_1(kt, ds) do {                                                      \
    gload16(b1[0] + (size_t)(kt) * 64, Bs + (ds) * 12288 + 0 * 2048 + doff);   \
    gload16(b1[1] + (size_t)(kt) * 64, Bs + (ds) * 12288 + 1 * 2048 + doff);   \
    gload16(b1[2] + (size_t)(kt) * 64, Bs + (ds) * 12288 + 2 * 2048 + doff);   \
    gload16(b1[3] + (size_t)(kt) * 64, Bs + (ds) * 12288 + 3 * 2048 + doff); } while (0)
#define I1_1(kt, ds) do {                                                      \
    gload16(b1[4] + (size_t)(kt) * 64, Bs + (ds) * 12288 + 4 * 2048 + doff);   \
    gload16(b1[5] + (size_t)(kt) * 64, Bs + (ds) * 12288 + 5 * 2048 + doff);   \
    gload16(a1[0] + (size_t)(kt) * 64, As + (ds) * 8192 + 0 * 2048 + doff);    \
    gload16(a1[1] + (size_t)(kt) * 64, As + (ds) * 8192 + 1 * 2048 + doff); } while (0)
#define I2_1(kt, ds) do {                                                      \
    gload16(a1[2] + (size_t)(kt) * 64, As + (ds) * 8192 + 2 * 2048 + doff);    \
    gload16(a1[3] + (size_t)(kt) * 64, As + (ds) * 8192 + 3 * 2048 + doff); } while (0)
// phase2 staging groups (k2 in units of 64 along K=256)
#define I0_2(k2, ds) do {                                                      \
    gload16(b2[0] + (size_t)(k2) * 64, Bs + (ds) * 12288 + 0 * 2048 + doff);   \
    gload16(b2[1] + (size_t)(k2) * 64, Bs + (ds) * 12288 + 1 * 2048 + doff);   \
    gload16(b2[2] + (size_t)(k2) * 64, Bs + (ds) * 12288 + 2 * 2048 + doff);   \
    gload16(b2[3] + (size_t)(k2) * 64, Bs + (ds) * 12288 + 3 * 2048 + doff); } while (0)
#define I1_2(k2, ds) do {                                                      \
    gload16(b2[4] + (size_t)(k2) * 64, Bs + (ds) * 12288 + 4 * 2048 + doff);   \
    gload16(b2[5] + (size_t)(k2) * 64, Bs + (ds) * 12288 + 5 * 2048 + doff);   \
    gload16(a2[0] + (size_t)(k2) * 64, As + (ds) * 8192 + 0 * 2048 + doff);    \
    gload16(a2[1] + (size_t)(k2) * 64, As + (ds) * 8192 + 1 * 2048 + doff); } while (0)
#define I2_2(k2, ds) do {                                                      \
    gload16(a2[2] + (size_t)(k2) * 64, As + (ds) * 8192 + 2 * 2048 + doff);    \
    gload16(a2[3] + (size_t)(k2) * 64, As + (ds) * 8192 + 3 * 2048 + doff); } while (0)

// One K-tile (slot sl). Phase pattern: reads -> barrier -> lgkm0 -> MFMA.
#define KSTEP(slot_, I0, W0, I1, I2, NT) do {                                  \
    const unsigned short* aS = As + (slot_) * 8192;                            \
    const unsigned short* bS = Bs + (slot_) * 12288;                           \
    I0;                                                                        \
    asm volatile("s_waitcnt vmcnt(" W0 ")" ::: "memory");                      \
    __builtin_amdgcn_s_barrier();                                              \
    RDBV(kb0); RDAV(0, kb0);                                                   \
    __builtin_amdgcn_s_barrier();                                              \
    MM12(0, NT);                                                               \
    RDAV(2, kb0);                                                              \
    I1;                                                                        \
    __builtin_amdgcn_s_barrier();                                              \
    MM12(2, NT);                                                               \
    RDBV(kb1); RDAV(0, kb1);                                                   \
    I2;                                                                        \
    __builtin_amdgcn_s_barrier();                                              \
    MM12(0, NT);                                                               \
    RDAV(2, kb1);                                                              \
    __builtin_amdgcn_s_barrier();                                              \
    MM12(2, NT);                                                               \
} while (0)

__global__ __launch_bounds__(256, 2)
void gru_fused(const unsigned short* __restrict__ Xb,    // [8192][1024] bf16
               const unsigned short* __restrict__ Wirb,  // [6144][1024] bf16
               const unsigned short* __restrict__ Hbb,   // [8192][2048] bf16
               const unsigned short* __restrict__ Whb,   // [8][768][256] bf16
               const float* __restrict__ b_ir_lin,       // [6144]
               const float* __restrict__ b_ir,           // [6144]
               const float* __restrict__ b_hr,           // [6144]
               float* __restrict__ out) {                // [8192][2048] f32
    constexpr int K1 = 1024, H = 2048;
    __shared__ unsigned short lds[2 * 8192 + 2 * 12288];   // 80 KiB
    unsigned short* const As = lds;
    unsigned short* const Bs = lds + 2 * 8192;

    const int tid  = threadIdx.x;
    const int lane = tid & 63;
    const int w    = tid >> 6;   // 0..3
    const int wm   = w >> 1;     // 0..1 (64-row half)
    const int wn   = w & 1;      // 0..1 (32-col half)

    // Grid: 2048 = 8 kb (XCD-exclusive) x 64 bm x 4 hsub (hsub innermost).
    const int bid  = blockIdx.x;
    const int kb   = bid & 7;
    const int idx  = bid >> 3;          // 0..255
    const int bm   = (idx >> 2) * 128;
    const int hsub = idx & 3;
    const int hcb  = kb * 256 + hsub * 64;   // h-column base

    // ---- staging sources (inverse-swizzled global, linear LDS dest)
    const int srow  = tid >> 3;                 // 0..31 (row within 32-row chunk)
    const int chunk = (tid & 7) ^ (srow & 7);   // T2 XOR involution
    const int scol  = chunk * 8;
    const int doff  = tid * 8;                  // element offset within a chunk
    const unsigned short* a1[4];
    const unsigned short* a2[4];
    #pragma unroll
    for (int q = 0; q < 4; ++q) {
        a1[q] = Xb  + (size_t)(bm + q * 32 + srow) * K1 + scol;
        a2[q] = Hbb + (size_t)(bm + q * 32 + srow) * H + kb * 256 + scol;
    }
    const unsigned short* b1[6];
    const unsigned short* b2[6];
    #pragma unroll
    for (int q = 0; q < 6; ++q) {
        const int s  = q >> 1;
        const int rr = (q & 1) * 32 + srow;
        b1[q] = Wirb + (size_t)(s * 2048 + hcb + rr) * K1 + scol;
        b2[q] = Whb + (size_t)kb * 196608 + (size_t)(s * 256 + hsub * 64 + rr) * 256 + scol;
    }

    // ---- fragment read offsets (swizzled reads, rows are 128 B)
    const int fr  = lane & 15;
    const int k0e = (lane >> 4) * 8;
    const int mfr = (fr & 7) << 4;
    const int kb0 = ((k0e * 2) ^ mfr) >> 1;
    const int kb1 = (((k0e * 2) + 64) ^ mfr) >> 1;

    f32x4 acc[4][4][2] = {};   // [group][m-frag][n-frag]
    bf16x8 av[2], bv[3][2];

    // ---- prologue: stage tile 0 (phase1) — loads fly during the stagger
    I0_1(0, 0); I1_1(0, 0); I2_1(0, 0);

    // ---- convoy-break: anti-phase the co-resident block pair (~960 cyc)
    if (((bid >> 3) ^ (bid >> 8)) & 1) {
        __builtin_amdgcn_s_sleep(15);
    }

    // ---- phase1: tiles 0..14 (stage t+1, phase1)
    #pragma unroll 1
    for (int t = 0; t < 15; ++t) {
        const int sl = t & 1, nx = sl ^ 1;
        KSTEP(sl, I0_1(t + 1, nx), "4", I1_1(t + 1, nx), I2_1(t + 1, nx), 2);
    }
    // ---- bridge: compute tile 15 (phase1), stage tile 16 (phase2, k2=0)
    KSTEP(1, I0_2(0, 0), "4", I1_2(0, 0), I2_2(0, 0), 2);
    // ---- phase2: tiles 16..18 (stage k2 = t-15)
    #pragma unroll 1
    for (int t = 16; t < 19; ++t) {
        const int sl = t & 1, nx = sl ^ 1;
        KSTEP(sl, I0_2(t - 15, nx), "4", I1_2(t - 15, nx), I2_2(t - 15, nx), 3);
    }
    // ---- peel: tile 19, drain
    KSTEP(1, ((void)0), "0", ((void)0), ((void)0), 3);

    // ---- gate epilogue (h read as bf16)
    const int rq = (lane >> 4) * 4;
    #pragma unroll
    for (int n = 0; n < 2; ++n) {
        const int hcol = hcb + wn * 32 + n * 16 + fr;   // 0..2047
        const int lcol = hcol & 255;                    // within diagonal block
        const float bir0 = b_ir_lin[hcol]        + b_ir[hcol];
        const float bir1 = b_ir_lin[2048 + hcol] + b_ir[2048 + hcol];
        const float bir2 = b_ir_lin[4096 + hcol] + b_ir[4096 + hcol];
        const float bhr0 = b_hr[kb * 768 + lcol];
        const float bhr1 = b_hr[kb * 768 + 256 + lcol];
        const float bhr2 = b_hr[kb * 768 + 512 + lcol];
        #pragma unroll
        for (int mi = 0; mi < 4; ++mi) {
            #pragma unroll
            for (int r = 0; r < 4; ++r) {
                const int row = bm + wm * 64 + mi * 16 + rq + r;
                const float pr = acc[0][mi][n][r] + bir0 + bhr0;
                const float pz = acc[1][mi][n][r] + bir1 + bhr1;
                const float xn = acc[2][mi][n][r] + bir2;
                const float hn = acc[3][mi][n][r] + bhr2;
                const float rg = sigmoidf_(pr);
                const float zg = sigmoidf_(pz);
                const float ng = tanhf_(xn + rg * hn);
                const float hv = bf2f(Hbb[(size_t)row * H + hcol]);
                out[(size_t)row * H + hcol] = (1.0f - zg) * hv + zg * ng;
            }
        }
    }
}

// ---------------------------------------------------------------- launch
extern "C" void kernel_launch(void* const* d_in, const int* in_sizes, int n_in,
                              void* d_out, int out_size, void* d_ws, size_t ws_size,
                              hipStream_t stream) {
    const float* x        = (const float*)d_in[0];
    const float* h        = (const float*)d_in[1];
    const float* W_ir     = (const float*)d_in[2];
    const float* b_ir_lin = (const float*)d_in[3];
    const float* b_ir     = (const float*)d_in[4];
    const float* W_h      = (const float*)d_in[5];
    const float* b_hr     = (const float*)d_in[6];
    float* out = (float*)d_out;

    char* ws = (char*)d_ws;
    unsigned short* xb   = (unsigned short*)(ws);               // 16 MiB
    unsigned short* wirb = (unsigned short*)(ws + 16777216);    // 12 MiB
    unsigned short* hb   = (unsigned short*)(ws + 29360128);    // 32 MiB
    unsigned short* whb  = (unsigned short*)(ws + 62914560);    //  3 MiB

    cast_all<<<32256, 256, 0, stream>>>(x, W_ir, h, W_h, xb, wirb, hb, whb);

    gru_fused<<<2048, 256, 0, stream>>>(xb, wirb, hb, whb,
                                        b_ir_lin, b_ir, b_hr, out);
}

// Round 15
// 167.040 us; speedup vs baseline: 1.0222x; 1.0222x over previous
//
#include <hip/hip_runtime.h>
#include <cstdint>
#include <cstddef>

// Block-diagonal GRU on MI355X (gfx950), fully fused bf16 MFMA path.
// B=8192, IN=1024, H=2048, NB=8, BS=256, 3H=6144.
// Round 15: R9 rotated pipeline (register-independent MFMA vs reads via
// half-tile ping-pong) + T19 sched_group_barrier FORCED interleave:
// each half-K-tile emits {5 VMEM stage, (2 ds_read, 5 MFMA) x 5} so the
// matrix pipe stays busy while the LDS port drains — the AITER 1:1
// MFMA<->load pattern the compiler refuses to produce on its own
// (R9 proved independence alone is insufficient; m137 proved forcing
// without independence is insufficient; this is the untested combination).

typedef __attribute__((ext_vector_type(8))) short bf16x8;
typedef __attribute__((ext_vector_type(4))) float f32x4;

__device__ __forceinline__ unsigned short f2bf(float f) {
    uint32_t u = __float_as_uint(f);
    u += 0x7FFFu + ((u >> 16) & 1u);   // round-to-nearest-even
    return (unsigned short)(u >> 16);
}
__device__ __forceinline__ float bf2f(unsigned short b) {
    return __uint_as_float(((uint32_t)b) << 16);
}

__device__ __forceinline__ void gload16(const void* g, void* l) {
    __builtin_amdgcn_global_load_lds(
        (const __attribute__((address_space(1))) void*)g,
        (__attribute__((address_space(3))) void*)l,
        16, 0, 0);
}

__device__ __forceinline__ float sigmoidf_(float x) {
    return 1.0f / (1.0f + __expf(-x));
}
__device__ __forceinline__ float tanhf_(float x) {
    float e = __expf(-2.0f * fabsf(x));
    float t = (1.0f - e) / (1.0f + e);
    return copysignf(t, x);
}

// ---------------------------------------------------------------- one cast
// regions (in float4 units): x 2097152 | W_ir 1572864 | h 4194304 | W_h 393216
__global__ __launch_bounds__(256)
void cast_all(const float* __restrict__ x, const float* __restrict__ wir,
              const float* __restrict__ h, const float* __restrict__ wh,
              unsigned short* __restrict__ xb, unsigned short* __restrict__ wirb,
              unsigned short* __restrict__ hb, unsigned short* __restrict__ whb) {
    const int i = blockIdx.x * 256 + threadIdx.x;
    const float* s; unsigned short* d; int j;
    if (i < 2097152)      { s = x;   d = xb;   j = i; }
    else if (i < 3670016) { s = wir; d = wirb; j = i - 2097152; }
    else if (i < 7864320) { s = h;   d = hb;   j = i - 3670016; }
    else                  { s = wh;  d = whb;  j = i - 7864320; }
    const float4 v = *reinterpret_cast<const float4*>(s + (size_t)j * 4);
    ushort4 o;
    o.x = f2bf(v.x); o.y = f2bf(v.y); o.z = f2bf(v.z); o.w = f2bf(v.w);
    *reinterpret_cast<ushort4*>(d + (size_t)j * 4) = o;
}

// ---------------------------------------------------------------- fused GRU
// acc groups: 0=r(sum), 1=z(sum), 2=wxn, 3=whn. NT = 2 (phase1) / 3 (phase2).

#define MM24(AV, BV, NT) do {                                                  \
    _Pragma("unroll")                                                          \
    for (int m_ = 0; m_ < 4; ++m_) {                                           \
        acc[0][m_][0] = __builtin_amdgcn_mfma_f32_16x16x32_bf16(               \
            AV[m_], BV[0][0], acc[0][m_][0], 0, 0, 0);                         \
        acc[0][m_][1] = __builtin_amdgcn_mfma_f32_16x16x32_bf16(               \
            AV[m_], BV[0][1], acc[0][m_][1], 0, 0, 0);                         \
        acc[1][m_][0] = __builtin_amdgcn_mfma_f32_16x16x32_bf16(               \
            AV[m_], BV[1][0], acc[1][m_][0], 0, 0, 0);                         \
        acc[1][m_][1] = __builtin_amdgcn_mfma_f32_16x16x32_bf16(               \
            AV[m_], BV[1][1], acc[1][m_][1], 0, 0, 0);                         \
        acc[NT][m_][0] = __builtin_amdgcn_mfma_f32_16x16x32_bf16(              \
            AV[m_], BV[2][0], acc[NT][m_][0], 0, 0, 0);                        \
        acc[NT][m_][1] = __builtin_amdgcn_mfma_f32_16x16x32_bf16(              \
            AV[m_], BV[2][1], acc[NT][m_][1], 0, 0, 0);                        \
    }                                                                          \
} while (0)

// fragment reads (swizzled LDS, rows 128 B); sl and offsets are literals
#define RDSET(AV, BV, sl, kbx) do {                                            \
    _Pragma("unroll")                                                          \
    for (int m_ = 0; m_ < 4; ++m_)                                             \
        AV[m_] = *(const bf16x8*)(pAr[sl] + m_ * 1024 + (kbx));                \
    _Pragma("unroll")                                                          \
    for (int s_ = 0; s_ < 3; ++s_) {                                           \
        BV[s_][0] = *(const bf16x8*)(pBr[sl] + s_ * 4096 + (kbx));             \
        BV[s_][1] = *(const bf16x8*)(pBr[sl] + s_ * 4096 + 1024 + (kbx));      \
    }                                                                          \
} while (0)

// T19 forced interleave for one half-K-tile scheduling region:
// pull 5 VMEM (stage) up, then alternate {2 ds_read, 5 MFMA} x 5.
#define SGB_HALF() do {                                                        \
    __builtin_amdgcn_sched_group_barrier(0x010, 5, 0);                         \
    _Pragma("unroll")                                                          \
    for (int g_ = 0; g_ < 5; ++g_) {                                           \
        __builtin_amdgcn_sched_group_barrier(0x100, 2, 0);                     \
        __builtin_amdgcn_sched_group_barrier(0x008, 5, 0);                     \
    }                                                                          \
} while (0)

// staging: 10 gloads per K-tile; base + compile-time offsets (elements)
#define I_1(kt, ds) do {                                                       \
    gload16(XbB  + 0 * 32768   + (kt) * 64, As + (ds) * 8192 + 0 * 2048 + doff); \
    gload16(XbB  + 1 * 32768   + (kt) * 64, As + (ds) * 8192 + 1 * 2048 + doff); \
    gload16(XbB  + 2 * 32768   + (kt) * 64, As + (ds) * 8192 + 2 * 2048 + doff); \
    gload16(XbB  + 3 * 32768   + (kt) * 64, As + (ds) * 8192 + 3 * 2048 + doff); \
    gload16(WirB + 0 * 2097152 + 0 * 32768 + (kt) * 64, Bs + (ds) * 12288 + 0 * 2048 + doff); \
    gload16(WirB + 0 * 2097152 + 1 * 32768 + (kt) * 64, Bs + (ds) * 12288 + 1 * 2048 + doff); \
    gload16(WirB + 1 * 2097152 + 0 * 32768 + (kt) * 64, Bs + (ds) * 12288 + 2 * 2048 + doff); \
    gload16(WirB + 1 * 2097152 + 1 * 32768 + (kt) * 64, Bs + (ds) * 12288 + 3 * 2048 + doff); \
    gload16(WirB + 2 * 2097152 + 0 * 32768 + (kt) * 64, Bs + (ds) * 12288 + 4 * 2048 + doff); \
    gload16(WirB + 2 * 2097152 + 1 * 32768 + (kt) * 64, Bs + (ds) * 12288 + 5 * 2048 + doff); \
} while (0)
#define I_2(k2, ds) do {                                                       \
    gload16(XhB + 0 * 65536 + (k2) * 64, As + (ds) * 8192 + 0 * 2048 + doff);  \
    gload16(XhB + 1 * 65536 + (k2) * 64, As + (ds) * 8192 + 1 * 2048 + doff);  \
    gload16(XhB + 2 * 65536 + (k2) * 64, As + (ds) * 8192 + 2 * 2048 + doff);  \
    gload16(XhB + 3 * 65536 + (k2) * 64, As + (ds) * 8192 + 3 * 2048 + doff);  \
    gload16(WhB + 0 * 65536 + 0 * 8192 + (k2) * 64, Bs + (ds) * 12288 + 0 * 2048 + doff); \
    gload16(WhB + 0 * 65536 + 1 * 8192 + (k2) * 64, Bs + (ds) * 12288 + 1 * 2048 + doff); \
    gload16(WhB + 1 * 65536 + 0 * 8192 + (k2) * 64, Bs + (ds) * 12288 + 2 * 2048 + doff); \
    gload16(WhB + 1 * 65536 + 1 * 8192 + (k2) * 64, Bs + (ds) * 12288 + 3 * 2048 + doff); \
    gload16(WhB + 2 * 65536 + 0 * 8192 + (k2) * 64, Bs + (ds) * 12288 + 4 * 2048 + doff); \
    gload16(WhB + 2 * 65536 + 1 * 8192 + (k2) * 64, Bs + (ds) * 12288 + 5 * 2048 + doff); \
} while (0)

// Rotated body for tile t (slot sl = t&1):
//   lgkm0 (slot-safety: all prior reads complete) ; vmcnt0 (stage(t) landed,
//   issued a full body ago -> ~free) ; barrier ; stage(t+1 -> sl^1) ;
//   [reads kb0(t) || MFMA kb1(t-1)]  <- SGB-forced interleave
//   [reads kb1(t) || MFMA kb0(t)]    <- SGB-forced interleave
//   sched_barrier(0) fences the region per body.
#define BODY(sl, STAGE, NTp, NTc) do {                                         \
    asm volatile("s_waitcnt lgkmcnt(0)" ::: "memory");                         \
    asm volatile("s_waitcnt vmcnt(0)" ::: "memory");                           \
    __builtin_amdgcn_s_barrier();                                              \
    STAGE;                                                                     \
    RDSET(avA, bvA, sl, kb0);                                                  \
    MM24(avB, bvB, NTp);                                                       \
    SGB_HALF();                                                                \
    RDSET(avB, bvB, sl, kb1);                                                  \
    MM24(avA, bvA, NTc);                                                       \
    SGB_HALF();                                                                \
    __builtin_amdgcn_sched_barrier(0);                                         \
} while (0)

__global__ __launch_bounds__(256, 2)
void gru_fused(const unsigned short* __restrict__ Xb,    // [8192][1024] bf16
               const unsigned short* __restrict__ Wirb,  // [6144][1024] bf16
               const unsigned short* __restrict__ Hbb,   // [8192][2048] bf16
               const unsigned short* __restrict__ Whb,   // [8][768][256] bf16
               const float* __restrict__ b_ir_lin,       // [6144]
               const float* __restrict__ b_ir,           // [6144]
               const float* __restrict__ b_hr,           // [6144]
               float* __restrict__ out) {                // [8192][2048] f32
    constexpr int K1 = 1024, H = 2048;
    __shared__ unsigned short lds[2 * 8192 + 2 * 12288];   // 80 KiB
    unsigned short* const As = lds;
    unsigned short* const Bs = lds + 2 * 8192;

    const int tid  = threadIdx.x;
    const int lane = tid & 63;
    const int w    = tid >> 6;   // 0..3
    const int wm   = w >> 1;     // 0..1 (64-row half)
    const int wn   = w & 1;      // 0..1 (32-col half)

    // Grid: 2048 = 8 kb (XCD-exclusive) x 64 bm x 4 hsub (hsub innermost).
    const int bid  = blockIdx.x;
    const int kb   = bid & 7;
    const int idx  = bid >> 3;
    const int bm   = (idx >> 2) * 128;
    const int hsub = idx & 3;
    const int hcb  = kb * 256 + hsub * 64;   // h-column base

    // ---- staging bases (inverse-swizzled global, linear LDS dest, T2/G21)
    const int srow  = tid >> 3;                 // 0..31 (row within 32-row chunk)
    const int chunk = (tid & 7) ^ (srow & 7);   // XOR involution
    const int scol  = chunk * 8;
    const int doff  = tid * 8;
    const unsigned short* XbB  = Xb   + (size_t)(bm + srow) * K1 + scol;
    const unsigned short* WirB = Wirb + (size_t)(hcb + srow) * K1 + scol;
    const unsigned short* XhB  = Hbb  + (size_t)(bm + srow) * H + kb * 256 + scol;
    const unsigned short* WhB  = Whb  + (size_t)kb * 196608
                                      + (size_t)(hsub * 64 + srow) * 256 + scol;

    // ---- fragment read bases (swizzled reads, rows are 128 B)
    const int fr  = lane & 15;
    const int k0e = (lane >> 4) * 8;
    const int mfr = (fr & 7) << 4;
    const int kb0 = ((k0e * 2) ^ mfr) >> 1;
    const int kb1 = (((k0e * 2) + 64) ^ mfr) >> 1;
    const unsigned short* pAr[2];
    const unsigned short* pBr[2];
    pAr[0] = As + (wm * 64 + fr) * 64;
    pAr[1] = As + 8192 + (wm * 64 + fr) * 64;
    pBr[0] = Bs + (wn * 32 + fr) * 64;
    pBr[1] = Bs + 12288 + (wn * 32 + fr) * 64;

    f32x4 acc[4][4][2] = {};   // [group][m-frag][n-frag]
    bf16x8 avA[4], avB[4], bvA[3][2], bvB[3][2];

    // ---- prologue: stage tile 0, then tile 1; compute tile0 kb0; defer kb1
    I_1(0, 0);
    asm volatile("s_waitcnt vmcnt(0)" ::: "memory");
    __builtin_amdgcn_s_barrier();
    I_1(1, 1);
    RDSET(avA, bvA, 0, kb0);
    RDSET(avB, bvB, 0, kb1);
    MM24(avA, bvA, 2);

    // ---- tiles 1..14 (phase1)
    BODY(1, I_1(2, 0),  2, 2);
    BODY(0, I_1(3, 1),  2, 2);
    BODY(1, I_1(4, 0),  2, 2);
    BODY(0, I_1(5, 1),  2, 2);
    BODY(1, I_1(6, 0),  2, 2);
    BODY(0, I_1(7, 1),  2, 2);
    BODY(1, I_1(8, 0),  2, 2);
    BODY(0, I_1(9, 1),  2, 2);
    BODY(1, I_1(10, 0), 2, 2);
    BODY(0, I_1(11, 1), 2, 2);
    BODY(1, I_1(12, 0), 2, 2);
    BODY(0, I_1(13, 1), 2, 2);
    BODY(1, I_1(14, 0), 2, 2);
    BODY(0, I_1(15, 1), 2, 2);
    // ---- tile 15 (last phase1), stage first phase2 tile
    BODY(1, I_2(0, 0),  2, 2);
    // ---- tiles 16..19 (phase2)
    BODY(0, I_2(1, 1),  2, 3);
    BODY(1, I_2(2, 0),  3, 3);
    BODY(0, I_2(3, 1),  3, 3);
    BODY(1, ((void)0),  3, 3);
    // ---- tail: deferred kb1 of tile 19
    asm volatile("s_waitcnt lgkmcnt(0)" ::: "memory");
    MM24(avB, bvB, 3);

    // ---- gate epilogue (h read as bf16)
    const int rq = (lane >> 4) * 4;
    #pragma unroll
    for (int n = 0; n < 2; ++n) {
        const int hcol = hcb + wn * 32 + n * 16 + fr;   // 0..2047
        const int lcol = hcol & 255;                    // within diagonal block
        const float bir0 = b_ir_lin[hcol]        + b_ir[hcol];
        const float bir1 = b_ir_lin[2048 + hcol] + b_ir[2048 + hcol];
        const float bir2 = b_ir_lin[4096 + hcol] + b_ir[4096 + hcol];
        const float bhr0 = b_hr[kb * 768 + lcol];
        const float bhr1 = b_hr[kb * 768 + 256 + lcol];
        const float bhr2 = b_hr[kb * 768 + 512 + lcol];
        #pragma unroll
        for (int mi = 0; mi < 4; ++mi) {
            #pragma unroll
            for (int r = 0; r < 4; ++r) {
                const int row = bm + wm * 64 + mi * 16 + rq + r;
                const float pr = acc[0][mi][n][r] + bir0 + bhr0;
                const float pz = acc[1][mi][n][r] + bir1 + bhr1;
                const float xn = acc[2][mi][n][r] + bir2;
                const float hn = acc[3][mi][n][r] + bhr2;
                const float rg = sigmoidf_(pr);
                const float zg = sigmoidf_(pz);
                const float ng = tanhf_(xn + rg * hn);
                const float hv = bf2f(Hbb[(size_t)row * H + hcol]);
                out[(size_t)row * H + hcol] = (1.0f - zg) * hv + zg * ng;
            }
        }
    }
}

// ---------------------------------------------------------------- launch
extern "C" void kernel_launch(void* const* d_in, const int* in_sizes, int n_in,
                              void* d_out, int out_size, void* d_ws, size_t ws_size,
                              hipStream_t stream) {
    const float* x        = (const float*)d_in[0];
    const float* h        = (const float*)d_in[1];
    const float* W_ir     = (const float*)d_in[2];
    const float* b_ir_lin = (const float*)d_in[3];
    const float* b_ir     = (const float*)d_in[4];
    const float* W_h      = (const float*)d_in[5];
    const float* b_hr     = (const float*)d_in[6];
    float* out = (float*)d_out;

    char* ws = (char*)d_ws;
    unsigned short* xb   = (unsigned short*)(ws);               // 16 MiB
    unsigned short* wirb = (unsigned short*)(ws + 16777216);    // 12 MiB
    unsigned short* hb   = (unsigned short*)(ws + 29360128);    // 32 MiB
    unsigned short* whb  = (unsigned short*)(ws + 62914560);    //  3 MiB

    cast_all<<<32256, 256, 0, stream>>>(x, W_ir, h, W_h, xb, wirb, hb, whb);

    gru_fused<<<2048, 256, 0, stream>>>(xb, wirb, hb, whb,
                                        b_ir_lin, b_ir, b_hr, out);
}

// Round 16
// 159.647 us; speedup vs baseline: 1.0696x; 1.0463x over previous
//
#include <hip/hip_runtime.h>
#include <cstdint>
#include <cstddef>

// Block-diagonal GRU on MI355X (gfx950), fully fused bf16 MFMA path.
// B=8192, IN=1024, H=2048, NB=8, BS=256, 3H=6144.
// Round 16: R15 GEMM (rotated pipeline + T19 forced interleave, best at
// 133us) + h-cast elimination: phase2 A-operand reg-stages h f32->bf16
// in-kernel (loads at body top, cvt + swizzled ds_write_b128 mid-body;
// write-side XOR swizzle replaces the inverse-swizzled-source trick),
// epilogue reads h f32 directly. Cast traffic 189MB -> 93MB (~15us saved).

typedef __attribute__((ext_vector_type(8))) short bf16x8;
typedef __attribute__((ext_vector_type(4))) float f32x4;

__device__ __forceinline__ unsigned short f2bf(float f) {
    uint32_t u = __float_as_uint(f);
    u += 0x7FFFu + ((u >> 16) & 1u);   // round-to-nearest-even
    return (unsigned short)(u >> 16);
}

__device__ __forceinline__ void gload16(const void* g, void* l) {
    __builtin_amdgcn_global_load_lds(
        (const __attribute__((address_space(1))) void*)g,
        (__attribute__((address_space(3))) void*)l,
        16, 0, 0);
}

__device__ __forceinline__ float sigmoidf_(float x) {
    return 1.0f / (1.0f + __expf(-x));
}
__device__ __forceinline__ float tanhf_(float x) {
    float e = __expf(-2.0f * fabsf(x));
    float t = (1.0f - e) / (1.0f + e);
    return copysignf(t, x);
}

// ---------------------------------------------------------------- cast
// regions (float4 units): x 2097152 | W_ir 1572864 | W_h 393216  (no h!)
__global__ __launch_bounds__(256)
void cast_all(const float* __restrict__ x, const float* __restrict__ wir,
              const float* __restrict__ wh,
              unsigned short* __restrict__ xb, unsigned short* __restrict__ wirb,
              unsigned short* __restrict__ whb) {
    const int i = blockIdx.x * 256 + threadIdx.x;
    const float* s; unsigned short* d; int j;
    if (i < 2097152)      { s = x;   d = xb;   j = i; }
    else if (i < 3670016) { s = wir; d = wirb; j = i - 2097152; }
    else                  { s = wh;  d = whb;  j = i - 3670016; }
    const float4 v = *reinterpret_cast<const float4*>(s + (size_t)j * 4);
    ushort4 o;
    o.x = f2bf(v.x); o.y = f2bf(v.y); o.z = f2bf(v.z); o.w = f2bf(v.w);
    *reinterpret_cast<ushort4*>(d + (size_t)j * 4) = o;
}

// ---------------------------------------------------------------- fused GRU
// acc groups: 0=r(sum), 1=z(sum), 2=wxn, 3=whn. NT = 2 (phase1) / 3 (phase2).

#define MM24(AV, BV, NT) do {                                                  \
    _Pragma("unroll")                                                          \
    for (int m_ = 0; m_ < 4; ++m_) {                                           \
        acc[0][m_][0] = __builtin_amdgcn_mfma_f32_16x16x32_bf16(               \
            AV[m_], BV[0][0], acc[0][m_][0], 0, 0, 0);                         \
        acc[0][m_][1] = __builtin_amdgcn_mfma_f32_16x16x32_bf16(               \
            AV[m_], BV[0][1], acc[0][m_][1], 0, 0, 0);                         \
        acc[1][m_][0] = __builtin_amdgcn_mfma_f32_16x16x32_bf16(               \
            AV[m_], BV[1][0], acc[1][m_][0], 0, 0, 0);                         \
        acc[1][m_][1] = __builtin_amdgcn_mfma_f32_16x16x32_bf16(               \
            AV[m_], BV[1][1], acc[1][m_][1], 0, 0, 0);                         \
        acc[NT][m_][0] = __builtin_amdgcn_mfma_f32_16x16x32_bf16(              \
            AV[m_], BV[2][0], acc[NT][m_][0], 0, 0, 0);                        \
        acc[NT][m_][1] = __builtin_amdgcn_mfma_f32_16x16x32_bf16(              \
            AV[m_], BV[2][1], acc[NT][m_][1], 0, 0, 0);                        \
    }                                                                          \
} while (0)

// fragment reads (swizzled LDS, rows 128 B); sl and offsets are literals
#define RDSET(AV, BV, sl, kbx) do {                                            \
    _Pragma("unroll")                                                          \
    for (int m_ = 0; m_ < 4; ++m_)                                             \
        AV[m_] = *(const bf16x8*)(pAr[sl] + m_ * 1024 + (kbx));                \
    _Pragma("unroll")                                                          \
    for (int s_ = 0; s_ < 3; ++s_) {                                           \
        BV[s_][0] = *(const bf16x8*)(pBr[sl] + s_ * 4096 + (kbx));             \
        BV[s_][1] = *(const bf16x8*)(pBr[sl] + s_ * 4096 + 1024 + (kbx));      \
    }                                                                          \
} while (0)

// T19 forced interleave: pull VMEM up, then alternate {2 ds_read, 5 MFMA} x 5.
#define SGB_HALF() do {                                                        \
    __builtin_amdgcn_sched_group_barrier(0x030, 5, 0);                         \
    _Pragma("unroll")                                                          \
    for (int g_ = 0; g_ < 5; ++g_) {                                           \
        __builtin_amdgcn_sched_group_barrier(0x100, 2, 0);                     \
        __builtin_amdgcn_sched_group_barrier(0x008, 5, 0);                     \
    }                                                                          \
} while (0)

// phase1 staging: 10 gloads per K-tile (unchanged from R15)
#define I_1(kt, ds) do {                                                       \
    gload16(XbB  + 0 * 32768   + (kt) * 64, As + (ds) * 8192 + 0 * 2048 + doff); \
    gload16(XbB  + 1 * 32768   + (kt) * 64, As + (ds) * 8192 + 1 * 2048 + doff); \
    gload16(XbB  + 2 * 32768   + (kt) * 64, As + (ds) * 8192 + 2 * 2048 + doff); \
    gload16(XbB  + 3 * 32768   + (kt) * 64, As + (ds) * 8192 + 3 * 2048 + doff); \
    gload16(WirB + 0 * 2097152 + 0 * 32768 + (kt) * 64, Bs + (ds) * 12288 + 0 * 2048 + doff); \
    gload16(WirB + 0 * 2097152 + 1 * 32768 + (kt) * 64, Bs + (ds) * 12288 + 1 * 2048 + doff); \
    gload16(WirB + 1 * 2097152 + 0 * 32768 + (kt) * 64, Bs + (ds) * 12288 + 2 * 2048 + doff); \
    gload16(WirB + 1 * 2097152 + 1 * 32768 + (kt) * 64, Bs + (ds) * 12288 + 3 * 2048 + doff); \
    gload16(WirB + 2 * 2097152 + 0 * 32768 + (kt) * 64, Bs + (ds) * 12288 + 4 * 2048 + doff); \
    gload16(WirB + 2 * 2097152 + 1 * 32768 + (kt) * 64, Bs + (ds) * 12288 + 5 * 2048 + doff); \
} while (0)
// phase2: B (W_h) DMA only; A (h) is reg-staged from f32
#define IB2(k2, ds) do {                                                       \
    gload16(WhB + 0 * 65536 + 0 * 8192 + (k2) * 64, Bs + (ds) * 12288 + 0 * 2048 + doff); \
    gload16(WhB + 0 * 65536 + 1 * 8192 + (k2) * 64, Bs + (ds) * 12288 + 1 * 2048 + doff); \
    gload16(WhB + 1 * 65536 + 0 * 8192 + (k2) * 64, Bs + (ds) * 12288 + 2 * 2048 + doff); \
    gload16(WhB + 1 * 65536 + 1 * 8192 + (k2) * 64, Bs + (ds) * 12288 + 3 * 2048 + doff); \
    gload16(WhB + 2 * 65536 + 0 * 8192 + (k2) * 64, Bs + (ds) * 12288 + 4 * 2048 + doff); \
    gload16(WhB + 2 * 65536 + 1 * 8192 + (k2) * 64, Bs + (ds) * 12288 + 5 * 2048 + doff); \
} while (0)
// h f32 loads (8 float4 -> regs) for phase2 A-tile k2
#define LOADH(k2) do {                                                         \
    _Pragma("unroll") for (int q_ = 0; q_ < 4; ++q_) {                         \
        hf[q_][0] = *(const float4*)(HfB + (size_t)q_ * 32 * H + (k2) * 64);   \
        hf[q_][1] = *(const float4*)(HfB + (size_t)q_ * 32 * H + (k2) * 64 + 4); \
    }                                                                          \
} while (0)
// cvt + swizzled ds_write of the staged h tile into A slot ds
#define WRITEH(ds) do {                                                        \
    _Pragma("unroll") for (int q_ = 0; q_ < 4; ++q_) {                         \
        bf16x8 o_;                                                             \
        o_[0] = (short)f2bf(hf[q_][0].x); o_[1] = (short)f2bf(hf[q_][0].y);    \
        o_[2] = (short)f2bf(hf[q_][0].z); o_[3] = (short)f2bf(hf[q_][0].w);    \
        o_[4] = (short)f2bf(hf[q_][1].x); o_[5] = (short)f2bf(hf[q_][1].y);    \
        o_[6] = (short)f2bf(hf[q_][1].z); o_[7] = (short)f2bf(hf[q_][1].w);    \
        *(bf16x8*)(As + (ds) * 8192 + q_ * 2048 + wof) = o_;                   \
    }                                                                          \
} while (0)
#define IH2(k2, ds) do { LOADH(k2); IB2(k2, ds); } while (0)

// Rotated body (R15) + optional mid-body WMID (cvt+write for phase2 A).
#define BODY(sl, STAGE, WMID, NTp, NTc) do {                                   \
    asm volatile("s_waitcnt lgkmcnt(0)" ::: "memory");                         \
    asm volatile("s_waitcnt vmcnt(0)" ::: "memory");                           \
    __builtin_amdgcn_s_barrier();                                              \
    STAGE;                                                                     \
    RDSET(avA, bvA, sl, kb0);                                                  \
    MM24(avB, bvB, NTp);                                                       \
    SGB_HALF();                                                                \
    WMID;                                                                      \
    RDSET(avB, bvB, sl, kb1);                                                  \
    MM24(avA, bvA, NTc);                                                       \
    SGB_HALF();                                                                \
    __builtin_amdgcn_sched_barrier(0);                                         \
} while (0)

__global__ __launch_bounds__(256, 2)
void gru_fused(const unsigned short* __restrict__ Xb,    // [8192][1024] bf16
               const unsigned short* __restrict__ Wirb,  // [6144][1024] bf16
               const float* __restrict__ Hf,             // [8192][2048] f32
               const unsigned short* __restrict__ Whb,   // [8][768][256] bf16
               const float* __restrict__ b_ir_lin,       // [6144]
               const float* __restrict__ b_ir,           // [6144]
               const float* __restrict__ b_hr,           // [6144]
               float* __restrict__ out) {                // [8192][2048] f32
    constexpr int K1 = 1024, H = 2048;
    __shared__ unsigned short lds[2 * 8192 + 2 * 12288];   // 80 KiB
    unsigned short* const As = lds;
    unsigned short* const Bs = lds + 2 * 8192;

    const int tid  = threadIdx.x;
    const int lane = tid & 63;
    const int w    = tid >> 6;   // 0..3
    const int wm   = w >> 1;     // 0..1 (64-row half)
    const int wn   = w & 1;      // 0..1 (32-col half)

    // Grid: 2048 = 8 kb (XCD-exclusive) x 64 bm x 4 hsub (hsub innermost).
    const int bid  = blockIdx.x;
    const int kb   = bid & 7;
    const int idx  = bid >> 3;
    const int bm   = (idx >> 2) * 128;
    const int hsub = idx & 3;
    const int hcb  = kb * 256 + hsub * 64;   // h-column base

    // ---- staging bases (phase1/B: inverse-swizzled global, linear LDS dest)
    const int srow  = tid >> 3;                 // 0..31 (row within 32-row chunk)
    const int chunk = (tid & 7) ^ (srow & 7);   // XOR involution
    const int scol  = chunk * 8;
    const int doff  = tid * 8;
    const unsigned short* XbB  = Xb   + (size_t)(bm + srow) * K1 + scol;
    const unsigned short* WirB = Wirb + (size_t)(hcb + srow) * K1 + scol;
    const unsigned short* WhB  = Whb  + (size_t)kb * 196608
                                      + (size_t)(hsub * 64 + srow) * 256 + scol;
    // phase2 A: linear f32 source (write-side swizzle instead)
    const float* HfB = Hf + (size_t)(bm + srow) * H + kb * 256 + (tid & 7) * 8;
    const int wof = (srow * 8 + ((tid & 7) ^ (srow & 7))) * 8;  // swizzled write

    // ---- fragment read bases (swizzled reads, rows are 128 B)
    const int fr  = lane & 15;
    const int k0e = (lane >> 4) * 8;
    const int mfr = (fr & 7) << 4;
    const int kb0 = ((k0e * 2) ^ mfr) >> 1;
    const int kb1 = (((k0e * 2) + 64) ^ mfr) >> 1;
    const unsigned short* pAr[2];
    const unsigned short* pBr[2];
    pAr[0] = As + (wm * 64 + fr) * 64;
    pAr[1] = As + 8192 + (wm * 64 + fr) * 64;
    pBr[0] = Bs + (wn * 32 + fr) * 64;
    pBr[1] = Bs + 12288 + (wn * 32 + fr) * 64;

    f32x4 acc[4][4][2] = {};   // [group][m-frag][n-frag]
    bf16x8 avA[4], avB[4], bvA[3][2], bvB[3][2];
    float4 hf[4][2];

    // ---- prologue: stage tile 0, then tile 1; compute tile0 kb0; defer kb1
    I_1(0, 0);
    asm volatile("s_waitcnt vmcnt(0)" ::: "memory");
    __builtin_amdgcn_s_barrier();
    I_1(1, 1);
    RDSET(avA, bvA, 0, kb0);
    RDSET(avB, bvB, 0, kb1);
    MM24(avA, bvA, 2);

    // ---- tiles 1..14 (phase1)
    BODY(1, I_1(2, 0),  ((void)0), 2, 2);
    BODY(0, I_1(3, 1),  ((void)0), 2, 2);
    BODY(1, I_1(4, 0),  ((void)0), 2, 2);
    BODY(0, I_1(5, 1),  ((void)0), 2, 2);
    BODY(1, I_1(6, 0),  ((void)0), 2, 2);
    BODY(0, I_1(7, 1),  ((void)0), 2, 2);
    BODY(1, I_1(8, 0),  ((void)0), 2, 2);
    BODY(0, I_1(9, 1),  ((void)0), 2, 2);
    BODY(1, I_1(10, 0), ((void)0), 2, 2);
    BODY(0, I_1(11, 1), ((void)0), 2, 2);
    BODY(1, I_1(12, 0), ((void)0), 2, 2);
    BODY(0, I_1(13, 1), ((void)0), 2, 2);
    BODY(1, I_1(14, 0), ((void)0), 2, 2);
    BODY(0, I_1(15, 1), ((void)0), 2, 2);
    // ---- tile 15 (last phase1), stage first phase2 tile (h reg-staged)
    BODY(1, IH2(0, 0),  WRITEH(0), 2, 2);
    // ---- tiles 16..19 (phase2)
    BODY(0, IH2(1, 1),  WRITEH(1), 2, 3);
    BODY(1, IH2(2, 0),  WRITEH(0), 3, 3);
    BODY(0, IH2(3, 1),  WRITEH(1), 3, 3);
    BODY(1, ((void)0),  ((void)0), 3, 3);
    // ---- tail: deferred kb1 of tile 19
    asm volatile("s_waitcnt lgkmcnt(0)" ::: "memory");
    MM24(avB, bvB, 3);

    // ---- gate epilogue (h read as f32 — closer to reference)
    const int rq = (lane >> 4) * 4;
    #pragma unroll
    for (int n = 0; n < 2; ++n) {
        const int hcol = hcb + wn * 32 + n * 16 + fr;   // 0..2047
        const int lcol = hcol & 255;                    // within diagonal block
        const float bir0 = b_ir_lin[hcol]        + b_ir[hcol];
        const float bir1 = b_ir_lin[2048 + hcol] + b_ir[2048 + hcol];
        const float bir2 = b_ir_lin[4096 + hcol] + b_ir[4096 + hcol];
        const float bhr0 = b_hr[kb * 768 + lcol];
        const float bhr1 = b_hr[kb * 768 + 256 + lcol];
        const float bhr2 = b_hr[kb * 768 + 512 + lcol];
        #pragma unroll
        for (int mi = 0; mi < 4; ++mi) {
            #pragma unroll
            for (int r = 0; r < 4; ++r) {
                const int row = bm + wm * 64 + mi * 16 + rq + r;
                const float pr = acc[0][mi][n][r] + bir0 + bhr0;
                const float pz = acc[1][mi][n][r] + bir1 + bhr1;
                const float xn = acc[2][mi][n][r] + bir2;
                const float hn = acc[3][mi][n][r] + bhr2;
                const float rg = sigmoidf_(pr);
                const float zg = sigmoidf_(pz);
                const float ng = tanhf_(xn + rg * hn);
                const float hv = Hf[(size_t)row * H + hcol];
                out[(size_t)row * H + hcol] = (1.0f - zg) * hv + zg * ng;
            }
        }
    }
}

// ---------------------------------------------------------------- launch
extern "C" void kernel_launch(void* const* d_in, const int* in_sizes, int n_in,
                              void* d_out, int out_size, void* d_ws, size_t ws_size,
                              hipStream_t stream) {
    const float* x        = (const float*)d_in[0];
    const float* h        = (const float*)d_in[1];
    const float* W_ir     = (const float*)d_in[2];
    const float* b_ir_lin = (const float*)d_in[3];
    const float* b_ir     = (const float*)d_in[4];
    const float* W_h      = (const float*)d_in[5];
    const float* b_hr     = (const float*)d_in[6];
    float* out = (float*)d_out;

    char* ws = (char*)d_ws;
    unsigned short* xb   = (unsigned short*)(ws);               // 16 MiB
    unsigned short* wirb = (unsigned short*)(ws + 16777216);    // 12 MiB
    unsigned short* whb  = (unsigned short*)(ws + 29360128);    //  3 MiB

    cast_all<<<15872, 256, 0, stream>>>(x, W_ir, W_h, xb, wirb, whb);

    gru_fused<<<2048, 256, 0, stream>>>(xb, wirb, h, whb,
                                        b_ir_lin, b_ir, b_hr, out);
}